// Round 19
// baseline (147.794 us; speedup 1.0000x reference)
//
#include <hip/hip_runtime.h>
#include <stdint.h>

typedef __attribute__((ext_vector_type(4))) float f32x4;
typedef __attribute__((ext_vector_type(16))) float f32x16;
typedef __attribute__((ext_vector_type(8))) short bf16x8;
typedef __attribute__((ext_vector_type(4))) short bf16x4;

#define MFMA16(a, b, c) __builtin_amdgcn_mfma_f32_16x16x32_bf16((a), (b), (c), 0, 0, 0)
#define MFMA32(a, b, c) __builtin_amdgcn_mfma_f32_32x32x16_bf16((a), (b), (c), 0, 0, 0)

__device__ __forceinline__ short f2bf(float f) {
    union { float f; uint32_t u; } v; v.f = f;
    uint32_t r = (v.u + 0x7fffu + ((v.u >> 16) & 1u)) >> 16;
    return (short)(uint16_t)r;
}
__device__ __forceinline__ float bf2f(short s) {
    union { uint32_t u; float f; } v; v.u = ((uint32_t)(uint16_t)s) << 16;
    return v.f;
}
__device__ __forceinline__ float fast_exp2(float x) {
    float r; asm("v_exp_f32 %0, %1" : "=v"(r) : "v"(x)); return r;
}

__device__ __forceinline__ void async_ld16(const short* g, short* l) {
    __builtin_amdgcn_global_load_lds(
        (const __attribute__((address_space(1))) uint32_t*)g,
        (__attribute__((address_space(3))) uint32_t*)l, 16, 0, 0);
}

#define MK_BFRAG(C, O, OUT) do {                                                   \
    uint32_t a_, b_, c_, d_;                                                       \
    asm("v_cvt_pk_bf16_f32 %0, %1, %2" : "=v"(a_) : "v"((C)[(O)+0]), "v"((C)[(O)+1])); \
    asm("v_cvt_pk_bf16_f32 %0, %1, %2" : "=v"(c_) : "v"((C)[(O)+2]), "v"((C)[(O)+3])); \
    asm("v_cvt_pk_bf16_f32 %0, %1, %2" : "=v"(b_) : "v"((C)[(O)+4]), "v"((C)[(O)+5])); \
    asm("v_cvt_pk_bf16_f32 %0, %1, %2" : "=v"(d_) : "v"((C)[(O)+6]), "v"((C)[(O)+7])); \
    asm("v_permlane32_swap_b32 %0, %1" : "+v"(a_), "+v"(b_));                      \
    asm("v_permlane32_swap_b32 %0, %1" : "+v"(c_), "+v"(d_));                      \
    union { uint32_t u[4]; bf16x8 v; } pb_;                                        \
    pb_.u[0] = a_; pb_.u[1] = c_; pb_.u[2] = b_; pb_.u[3] = d_;                    \
    OUT = pb_.v;                                                                   \
} while (0)

// ---------------------------------------------------------------------------
// convert_fused: blocks [0,2048) convert X fp32->bf16; [2048,2816) W -> Wt.
// ---------------------------------------------------------------------------
__global__ __launch_bounds__(256)
void convert_fused(const float* __restrict__ X, short* __restrict__ Xb,
                   const float* __restrict__ W, short* __restrict__ Wt) {
    __shared__ short T[64][72];
    const int t = threadIdx.x;
    const int id = blockIdx.x;
    if (id < 2048) {
        const int i8 = (id * 256 + t) << 3;
        f32x4 a = *(const f32x4*)(X + i8);
        f32x4 b = *(const f32x4*)(X + i8 + 4);
        bf16x8 o;
#pragma unroll
        for (int j = 0; j < 4; ++j) { o[j] = f2bf(a[j]); o[4 + j] = f2bf(b[j]); }
        *(bf16x8*)(Xb + i8) = o;
        return;
    }
    const int wid = id - 2048;
    const int n0 = (wid % 48) * 64, k0 = (wid / 48) * 64;
#pragma unroll
    for (int i = 0; i < 4; ++i) {
        const int r = i * 16 + (t >> 4);
        const int c = (t & 15) << 2;
        f32x4 v = *(const f32x4*)(W + (size_t)(k0 + r) * 3072 + n0 + c);
#pragma unroll
        for (int j = 0; j < 4; ++j) T[c + j][r] = f2bf(v[j]);
    }
    __syncthreads();
#pragma unroll
    for (int i = 0; i < 2; ++i) {
        const int r = i * 32 + (t >> 3);
        const int c = (t & 7) << 3;
        *(bf16x8*)(Wt + (size_t)(n0 + r) * 1024 + k0 + c) = *(const bf16x8*)&T[r][c];
    }
}

// ---------------------------------------------------------------------------
// gemm_pack v2 (unchanged): depth-2 prefetch, counted vmcnt(4), granule XOR
// swizzle; epilogue scatters into MFMA-frag-packed Qp/Kp/Vp; Q pre-scaled.
// ---------------------------------------------------------------------------
__global__ __launch_bounds__(256, 3)
void gemm_pack(const short* __restrict__ Xb, const short* __restrict__ Wt,
               const float* __restrict__ bias, short* __restrict__ Qp,
               short* __restrict__ Kp, short* __restrict__ Vp) {
    __shared__ short Asm[3][128 * 32];
    __shared__ short Bsm[3][128 * 32];

    const int tid  = threadIdx.x;
    const int lane = tid & 63;
    const int l15  = lane & 15;
    const int lq   = lane >> 4;
    const int wave = tid >> 6;
    const int wr = wave >> 1, wc = wave & 1;

    const int bid = blockIdx.x;
    const int swz = (bid & 7) * 96 + (bid >> 3);
    const int m0 = (swz / 24) * 128, n0 = (swz % 24) * 128;

    const int srow = tid >> 2;
    const int scolsw = (((tid & 3) ^ (srow & 3)) << 3);

    f32x4 acc[4][4];
#pragma unroll
    for (int m = 0; m < 4; ++m)
#pragma unroll
        for (int n = 0; n < 4; ++n) acc[m][n] = (f32x4)(0.0f);

    auto stage = [&](int k0, int bb) {
#pragma unroll
        for (int i = 0; i < 2; ++i)
            async_ld16(Xb + (size_t)(m0 + i * 64 + srow) * 1024 + k0 + scolsw,
                       &Asm[bb][(i * 256 + wave * 64) * 8]);
#pragma unroll
        for (int i = 0; i < 2; ++i)
            async_ld16(Wt + (size_t)(n0 + i * 64 + srow) * 1024 + k0 + scolsw,
                       &Bsm[bb][(i * 256 + wave * 64) * 8]);
    };

    const int gsw = ((lq ^ (l15 & 3)) << 3);

    auto compute = [&](int bb) {
        bf16x8 af[4], bfv[4];
#pragma unroll
        for (int m = 0; m < 4; ++m)
            af[m] = *(const bf16x8*)&Asm[bb][(wr * 64 + m * 16 + l15) * 32 + gsw];
#pragma unroll
        for (int n = 0; n < 4; ++n)
            bfv[n] = *(const bf16x8*)&Bsm[bb][(wc * 64 + n * 16 + l15) * 32 + gsw];
#pragma unroll
        for (int m = 0; m < 4; ++m)
#pragma unroll
            for (int n = 0; n < 4; ++n) acc[m][n] = MFMA16(af[m], bfv[n], acc[m][n]);
    };

#define WAITV(N) do {                                           \
        asm volatile("s_waitcnt vmcnt(" #N ")" ::: "memory");   \
        __builtin_amdgcn_sched_barrier(0);                      \
        __builtin_amdgcn_s_barrier();                           \
        __builtin_amdgcn_sched_barrier(0);                      \
    } while (0)

    stage(0, 0);
    stage(32, 1);
#pragma unroll 1
    for (int kt = 0; kt < 30; ++kt) {
        WAITV(4);
        compute(kt % 3);
        stage((kt + 2) * 32, (kt + 2) % 3);
    }
    WAITV(4);
    compute(0);
    WAITV(0);
    compute(1);
#undef WAITV

    const float SCALE2 = 0.03125f * 1.44269504f;
    float bv[4];
#pragma unroll
    for (int n = 0; n < 4; ++n) bv[n] = bias[n0 + wc * 64 + n * 16 + l15];

    const size_t bbase = (size_t)(m0 >> 11) * 2097152;
    const int tokb = (m0 & 2047) + wr * 64;

#pragma unroll
    for (int n = 0; n < 4; ++n) {
        const int col = n0 + wc * 64 + n * 16 + l15;
        const int h   = col / 192;
        const int seg = (col >> 6) % 3;
        const int d   = col & 63;
        const size_t hb = bbase + (size_t)h * 131072;
        if (seg == 0) {
            const int cp = ((d >> 4) << 9) + (((d >> 3) & 1) << 8) + (d & 7);
#pragma unroll
            for (int m = 0; m < 4; ++m)
#pragma unroll
                for (int r = 0; r < 4; ++r) {
                    const int tok = tokb + m * 16 + (lq << 2) + r;
                    Qp[hb + ((size_t)(tok >> 5) << 11) + ((tok & 31) << 3) + cp] =
                        f2bf((acc[m][n][r] + bv[n]) * SCALE2);
                }
        } else if (seg == 1) {
            const int cp = ((d >> 4) << 10) + (((d >> 3) & 1) << 8) + (d & 7);
#pragma unroll
            for (int m = 0; m < 4; ++m)
#pragma unroll
                for (int r = 0; r < 4; ++r) {
                    const int tok = tokb + m * 16 + (lq << 2) + r;
                    Kp[hb + ((size_t)(tok >> 6) << 12) + (((tok >> 5) & 1) << 9)
                       + ((tok & 31) << 3) + cp] = f2bf(acc[m][n][r] + bv[n]);
                }
        } else {
            const int cp = ((d >> 5) << 11) + ((d & 31) << 3);
#pragma unroll
            for (int m = 0; m < 4; ++m)
#pragma unroll
                for (int r = 0; r < 4; ++r) {
                    const int tok = tokb + m * 16 + (lq << 2) + r;
                    Vp[hb + ((size_t)(tok >> 6) << 12) + (((tok >> 4) & 3) << 9)
                       + (((tok >> 3) & 1) << 8) + (tok & 7) + cp] =
                        f2bf(acc[m][n][r] + bv[n]);
                }
        }
    }
}

// ---------------------------------------------------------------------------
// attn_part v14b: 4-wave cooperative chunk blocks; wave w handles tiles
// t0+w, t0+w+4, ... (private m/l/o, no per-tile barriers); ONE end-of-kernel
// LSE merge via padded LDS. FIX vs v14: diagonal kv-tile index is qt>>1
// (q-tiles are 32 rows, kv-tiles 64 wide), NOT qt.
// LPT chunk map (verified):
//   u<32 : head chunk, qt=u+32, tiles [0,16), no diag (qt>>1 >= 16)
//   u>=32: s=16-((u-32)>>2), j=(u-32)&3:
//          j<2 : qt=2s-2+j, tiles [0,s), diag tile = s-1
//          j>=2: qt=2s+30+(j-2), tiles [16,s+16), diag tile = s+15
// Decode: xcd=id&7, idx=id>>3, u=idx>>2, bh=xcd*4+(idx&3). Grid 3072 x 256.
// ---------------------------------------------------------------------------
__global__ __launch_bounds__(256, 3)
void attn_part(const short* __restrict__ Qp, const short* __restrict__ Kp,
               const short* __restrict__ Vp, short* __restrict__ Po,
               float* __restrict__ Pm) {
    __shared__ float oX[3][32 * 65];   // waves 1..3 partial O (f32), stride 65
    __shared__ float lmX[3][64];       // waves 1..3 {m, l} per row

    const int tid  = threadIdx.x;
    const int lane = tid & 63;
    const int l31  = tid & 31;
    const int hi   = (tid >> 5) & 1;
    const int w    = tid >> 6;        // wave 0..3

    const int id  = blockIdx.x;       // 0..3071
    const int xcd = id & 7;
    const int idx = id >> 3;          // 0..383
    const int u   = idx >> 2;         // 0..95 (LPT: sizes non-increasing)
    const int bh  = xcd * 4 + (idx & 3);

    int qt, t0, t1;
    if (u < 32) {
        qt = u + 32; t0 = 0; t1 = 16;
    } else {
        const int s = 16 - ((u - 32) >> 2);     // 16..1
        const int j = (u - 32) & 3;
        if (j < 2) { qt = 2 * s - 2 + j;        t0 = 0;  t1 = s; }
        else       { qt = 2 * s + 30 + (j - 2); t0 = 16; t1 = s + 16; }
    }
    const int q0 = qt * 32;
    const int dt = qt >> 1;           // diagonal kv-tile index

    const size_t hb = (size_t)bh * 131072;

    bf16x8 qf[4];
    {
        const short* qp = Qp + hb + qt * 2048 + lane * 8;
#pragma unroll
        for (int dg = 0; dg < 4; ++dg) qf[dg] = *(const bf16x8*)(qp + dg * 512);
    }

    f32x16 o0 = (f32x16)(0.f), o1 = (f32x16)(0.f);
    float m_run = -1e30f, l_run = 0.f;
    const int qg = q0 + l31;

    bf16x8 kA[8], kB[8], va[8];

    auto loadK = [&](bf16x8 (&kr)[8], int t) {
        const short* p = Kp + hb + (size_t)t * 4096 + lane * 8;
#pragma unroll
        for (int f = 0; f < 8; ++f)
            kr[f] = *(const bf16x8*)(p + (f >> 1) * 1024 + (f & 1) * 512);
    };
    auto loadV = [&](int t) {
        const short* p = Vp + hb + (size_t)t * 4096 + lane * 8;
#pragma unroll
        for (int f = 0; f < 8; ++f) va[f] = *(const bf16x8*)(p + f * 512);
    };
    auto qk = [&](bf16x8 (&kr)[8], f32x16& c0, f32x16& c1) {
#pragma unroll
        for (int dg = 0; dg < 4; ++dg) {
            c0 = MFMA32(kr[2 * dg],     qf[dg], c0);
            c1 = MFMA32(kr[2 * dg + 1], qf[dg], c1);
        }
    };

    auto smpv = [&](f32x16& c0, f32x16& c1, int kv0, bool DIAG) {
        if (DIAG) {
#pragma unroll
            for (int r = 0; r < 16; ++r) {
                const int kvr = kv0 + (r & 3) + 8 * (r >> 2) + 4 * hi;
                if (kvr > qg)      c0[r] = -1e30f;
                if (kvr + 32 > qg) c1[r] = -1e30f;
            }
        }

        float mr[8];
#pragma unroll
        for (int r = 0; r < 8; ++r)
            mr[r] = fmaxf(fmaxf(c0[r], c0[8 + r]), fmaxf(c1[r], c1[8 + r]));
        float mx = fmaxf(fmaxf(fmaxf(mr[0], mr[1]), fmaxf(mr[2], mr[3])),
                         fmaxf(fmaxf(mr[4], mr[5]), fmaxf(mr[6], mr[7])));
        mx = fmaxf(mx, __shfl_xor(mx, 32, 64));

        if (!__all(mx <= m_run + 8.f)) {              // T13 defer-rescale
            const float mnew = fmaxf(m_run, mx);
            const float corr = fast_exp2(m_run - mnew);
            l_run *= corr;
            o0 = o0 * corr;
            o1 = o1 * corr;
            m_run = mnew;
        }

        float ps0 = 0.f, ps1 = 0.f, ps2 = 0.f, ps3 = 0.f;
#pragma unroll
        for (int r = 0; r < 4; ++r) {
            c0[r]      = fast_exp2(c0[r]      - m_run); ps0 += c0[r];
            c0[4 + r]  = fast_exp2(c0[4 + r]  - m_run); ps1 += c0[4 + r];
            c0[8 + r]  = fast_exp2(c0[8 + r]  - m_run); ps2 += c0[8 + r];
            c0[12 + r] = fast_exp2(c0[12 + r] - m_run); ps3 += c0[12 + r];
        }
#pragma unroll
        for (int r = 0; r < 4; ++r) {
            c1[r]      = fast_exp2(c1[r]      - m_run); ps0 += c1[r];
            c1[4 + r]  = fast_exp2(c1[4 + r]  - m_run); ps1 += c1[4 + r];
            c1[8 + r]  = fast_exp2(c1[8 + r]  - m_run); ps2 += c1[8 + r];
            c1[12 + r] = fast_exp2(c1[12 + r] - m_run); ps3 += c1[12 + r];
        }
        l_run += (ps0 + ps1) + (ps2 + ps3);

        bf16x8 bf00, bf01, bf10, bf11;
        MK_BFRAG(c0, 0, bf00);
        MK_BFRAG(c0, 8, bf01);
        MK_BFRAG(c1, 0, bf10);
        MK_BFRAG(c1, 8, bf11);

        o0 = MFMA32(va[0], bf00, o0);
        o0 = MFMA32(va[1], bf01, o0);
        o0 = MFMA32(va[2], bf10, o0);
        o0 = MFMA32(va[3], bf11, o0);
        o1 = MFMA32(va[4], bf00, o1);
        o1 = MFMA32(va[5], bf01, o1);
        o1 = MFMA32(va[6], bf10, o1);
        o1 = MFMA32(va[7], bf11, o1);
    };

    // ---- wave-private stride-4 tile loop (K reg-dbuf across own tiles) ----
    int t = t0 + w;
    if (t < t1) {
        loadK(kA, t);
#pragma unroll 1
        while (t + 8 < t1) {
            f32x16 c0 = (f32x16)(0.f), c1 = (f32x16)(0.f);
            qk(kA, c0, c1);
            loadK(kB, t + 4);
            loadV(t);
            smpv(c0, c1, t * 64, t == dt);
            f32x16 d0 = (f32x16)(0.f), d1 = (f32x16)(0.f);
            qk(kB, d0, d1);
            loadK(kA, t + 8);
            loadV(t + 4);
            smpv(d0, d1, (t + 4) * 64, (t + 4) == dt);
            t += 8;
        }
        if (t + 4 < t1) {
            f32x16 c0 = (f32x16)(0.f), c1 = (f32x16)(0.f);
            qk(kA, c0, c1);
            loadK(kB, t + 4);
            loadV(t);
            smpv(c0, c1, t * 64, t == dt);
            f32x16 d0 = (f32x16)(0.f), d1 = (f32x16)(0.f);
            qk(kB, d0, d1);
            loadV(t + 4);
            smpv(d0, d1, (t + 4) * 64, (t + 4) == dt);
        } else {
            f32x16 c0 = (f32x16)(0.f), c1 = (f32x16)(0.f);
            qk(kA, c0, c1);
            loadV(t);
            smpv(c0, c1, t * 64, t == dt);
        }
    }

    // ---- in-block LSE merge (one barrier) ----
    const float l_tot = l_run + __shfl_xor(l_run, 32, 64);

    if (w > 0) {
        float* dst = &oX[w - 1][l31 * 65];
#pragma unroll
        for (int g = 0; g < 4; ++g) {
            f32x4 v0, v1;
#pragma unroll
            for (int j = 0; j < 4; ++j) { v0[j] = o0[4 * g + j]; v1[j] = o1[4 * g + j]; }
            *(f32x4*)&dst[8 * g + 4 * hi]      = v0;
            *(f32x4*)&dst[32 + 8 * g + 4 * hi] = v1;
        }
        if (hi == 0) { lmX[w - 1][l31 * 2] = m_run; lmX[w - 1][l31 * 2 + 1] = l_tot; }
    }
    __syncthreads();

    if (w == 0) {
        float mw[3], lw[3];
        float M = m_run;
#pragma unroll
        for (int i = 0; i < 3; ++i) {
            mw[i] = lmX[i][l31 * 2];
            lw[i] = lmX[i][l31 * 2 + 1];
            M = fmaxf(M, mw[i]);
        }
        const float wt0 = fast_exp2(m_run - M);
        float L = l_tot * wt0;
        float wts[3];
#pragma unroll
        for (int i = 0; i < 3; ++i) { wts[i] = fast_exp2(mw[i] - M); L += lw[i] * wts[i]; }

        f32x16 a0 = o0 * wt0, a1 = o1 * wt0;
#pragma unroll
        for (int i = 0; i < 3; ++i) {
            const float* src = &oX[i][l31 * 65];
#pragma unroll
            for (int g = 0; g < 4; ++g) {
                f32x4 v0 = *(const f32x4*)&src[8 * g + 4 * hi];
                f32x4 v1 = *(const f32x4*)&src[32 + 8 * g + 4 * hi];
#pragma unroll
                for (int j = 0; j < 4; ++j) {
                    a0[4 * g + j] += wts[i] * v0[j];
                    a1[4 * g + j] += wts[i] * v1[j];
                }
            }
        }

        const float inv = 1.f / L;
        const int prow = (bh * 96 + u) * 32 + l31;
#pragma unroll
        for (int g = 0; g < 4; ++g) {
            bf16x4 w4;
#pragma unroll
            for (int j = 0; j < 4; ++j) w4[j] = f2bf(a0[g * 4 + j] * inv);
            *(bf16x4*)&Po[(size_t)prow * 64 + 8 * g + 4 * hi] = w4;
#pragma unroll
            for (int j = 0; j < 4; ++j) w4[j] = f2bf(a1[g * 4 + j] * inv);
            *(bf16x4*)&Po[(size_t)prow * 64 + 32 + 8 * g + 4 * hi] = w4;
        }
        if (hi == 0) Pm[prow] = M + __log2f(L);
    }
}

// ---------------------------------------------------------------------------
// attn_combine (unchanged): merge <=2 partials per q-row -> fp32 Out.
//   qt < 32 : single partial, s=(qt>>1)+1, u = 32 + (16-s)*4 + (qt&1)
//   qt >= 32: head u0 = qt-32; tail s=(qt>>1)-15, u1 = 32+(16-s)*4+2+(qt&1)
// ---------------------------------------------------------------------------
__global__ __launch_bounds__(256)
void attn_combine(const short* __restrict__ Po, const float* __restrict__ Pm,
                  float* __restrict__ Out) {
    const int idx = blockIdx.x * 256 + threadIdx.x;
    const int d4 = (idx & 15) << 2;
    const int rg = idx >> 4;
    const int q  = rg & 2047;
    const int bh = rg >> 11;
    const int qt = q >> 5, r = q & 31;

    f32x4 ov;
    if (qt < 32) {
        const int s = (qt >> 1) + 1;
        const int u = 32 + (16 - s) * 4 + (qt & 1);
        const int p0 = (bh * 96 + u) * 32 + r;
        bf16x4 a = *(const bf16x4*)&Po[(size_t)p0 * 64 + d4];
#pragma unroll
        for (int j = 0; j < 4; ++j) ov[j] = bf2f(a[j]);
    } else {
        const int u0 = qt - 32;
        const int s  = (qt >> 1) - 15;
        const int u1 = 32 + (16 - s) * 4 + 2 + (qt & 1);
        const int p0 = (bh * 96 + u0) * 32 + r;
        const int p1 = (bh * 96 + u1) * 32 + r;
        bf16x4 a = *(const bf16x4*)&Po[(size_t)p0 * 64 + d4];
        bf16x4 c = *(const bf16x4*)&Po[(size_t)p1 * 64 + d4];
        const float m0 = Pm[p0], m1 = Pm[p1];
        const float M = fmaxf(m0, m1);
        const float w0 = exp2f(m0 - M), w1 = exp2f(m1 - M);
        const float inv = 1.f / (w0 + w1);
#pragma unroll
        for (int j = 0; j < 4; ++j) ov[j] = (w0 * bf2f(a[j]) + w1 * bf2f(c[j])) * inv;
    }
    *(f32x4*)&Out[(size_t)rg * 64 + d4] = ov;
}

extern "C" void kernel_launch(void* const* d_in, const int* in_sizes, int n_in,
                              void* d_out, int out_size, void* d_ws, size_t ws_size,
                              hipStream_t stream) {
    const float* x  = (const float*)d_in[0];
    const float* W0 = (const float*)d_in[1];
    const float* b0 = (const float*)d_in[2];
    float* out = (float*)d_out;
    char* ws = (char*)d_ws;

    const size_t SEG_B = (size_t)32 * 131072 * 2;     // 8.39 MB per packed segment
    const size_t QKV_B = 3 * SEG_B;                   // 25.17 MB (Qp+Kp+Vp)
    const size_t XBF_B = (size_t)4096 * 1024 * 2;     // 8.39 MB
    const size_t PO_B  = (size_t)32 * 96 * 32 * 64 * 2;  // 12.58 MB

    short* qp = (short*)ws;
    short* kp = (short*)(ws + SEG_B);
    short* vp = (short*)(ws + 2 * SEG_B);
    short* xb = (short*)(ws + QKV_B);
    short* wt = (short*)(ws + QKV_B + XBF_B);
    short* po = (short*)(ws + QKV_B);                 // reuse xb/wt after gemm
    float* pm = (float*)(ws + QKV_B + PO_B);

    convert_fused<<<dim3(2816), dim3(256), 0, stream>>>(x, xb, W0, wt);
    gemm_pack<<<dim3(768), dim3(256), 0, stream>>>(xb, wt, b0, qp, kp, vp);
    attn_part<<<dim3(3072), dim3(256), 0, stream>>>(qp, kp, vp, po, pm);
    attn_combine<<<dim3(4096), dim3(256), 0, stream>>>(po, pm, out);
}

// Round 20
// 84.137 us; speedup vs baseline: 1.7566x; 1.7566x over previous
//
#include <hip/hip_runtime.h>
#include <stdint.h>

typedef __attribute__((ext_vector_type(4))) float f32x4;
typedef __attribute__((ext_vector_type(16))) float f32x16;
typedef __attribute__((ext_vector_type(8))) short bf16x8;
typedef __attribute__((ext_vector_type(4))) short bf16x4;

#define MFMA16(a, b, c) __builtin_amdgcn_mfma_f32_16x16x32_bf16((a), (b), (c), 0, 0, 0)
#define MFMA32(a, b, c) __builtin_amdgcn_mfma_f32_32x32x16_bf16((a), (b), (c), 0, 0, 0)

__device__ __forceinline__ short f2bf(float f) {
    union { float f; uint32_t u; } v; v.f = f;
    uint32_t r = (v.u + 0x7fffu + ((v.u >> 16) & 1u)) >> 16;
    return (short)(uint16_t)r;
}
__device__ __forceinline__ float bf2f(short s) {
    union { uint32_t u; float f; } v; v.u = ((uint32_t)(uint16_t)s) << 16;
    return v.f;
}
__device__ __forceinline__ float fast_exp2(float x) {
    float r; asm("v_exp_f32 %0, %1" : "=v"(r) : "v"(x)); return r;
}

__device__ __forceinline__ void async_ld16(const short* g, short* l) {
    __builtin_amdgcn_global_load_lds(
        (const __attribute__((address_space(1))) uint32_t*)g,
        (__attribute__((address_space(3))) uint32_t*)l, 16, 0, 0);
}

// pack 8 exp'd P-values (regs O..O+7 of accumulator C) into the 32x32 B-frag
// for one kvslot via cvt_pk + permlane32_swap (lane<->lane+32 half exchange).
#define MK_BFRAG(C, O, OUT) do {                                                   \
    uint32_t a_, b_, c_, d_;                                                       \
    asm("v_cvt_pk_bf16_f32 %0, %1, %2" : "=v"(a_) : "v"((C)[(O)+0]), "v"((C)[(O)+1])); \
    asm("v_cvt_pk_bf16_f32 %0, %1, %2" : "=v"(c_) : "v"((C)[(O)+2]), "v"((C)[(O)+3])); \
    asm("v_cvt_pk_bf16_f32 %0, %1, %2" : "=v"(b_) : "v"((C)[(O)+4]), "v"((C)[(O)+5])); \
    asm("v_cvt_pk_bf16_f32 %0, %1, %2" : "=v"(d_) : "v"((C)[(O)+6]), "v"((C)[(O)+7])); \
    asm("v_permlane32_swap_b32 %0, %1" : "+v"(a_), "+v"(b_));                      \
    asm("v_permlane32_swap_b32 %0, %1" : "+v"(c_), "+v"(d_));                      \
    union { uint32_t u[4]; bf16x8 v; } pb_;                                        \
    pb_.u[0] = a_; pb_.u[1] = c_; pb_.u[2] = b_; pb_.u[3] = d_;                    \
    OUT = pb_.v;                                                                   \
} while (0)

// ---------------------------------------------------------------------------
// convert_fused: blocks [0,2048) convert X fp32->bf16; [2048,2816) W -> Wt.
// ---------------------------------------------------------------------------
__global__ __launch_bounds__(256)
void convert_fused(const float* __restrict__ X, short* __restrict__ Xb,
                   const float* __restrict__ W, short* __restrict__ Wt) {
    __shared__ short T[64][72];
    const int t = threadIdx.x;
    const int id = blockIdx.x;
    if (id < 2048) {
        const int i8 = (id * 256 + t) << 3;
        f32x4 a = *(const f32x4*)(X + i8);
        f32x4 b = *(const f32x4*)(X + i8 + 4);
        bf16x8 o;
#pragma unroll
        for (int j = 0; j < 4; ++j) { o[j] = f2bf(a[j]); o[4 + j] = f2bf(b[j]); }
        *(bf16x8*)(Xb + i8) = o;
        return;
    }
    const int wid = id - 2048;
    const int n0 = (wid % 48) * 64, k0 = (wid / 48) * 64;
#pragma unroll
    for (int i = 0; i < 4; ++i) {
        const int r = i * 16 + (t >> 4);
        const int c = (t & 15) << 2;
        f32x4 v = *(const f32x4*)(W + (size_t)(k0 + r) * 3072 + n0 + c);
#pragma unroll
        for (int j = 0; j < 4; ++j) T[c + j][r] = f2bf(v[j]);
    }
    __syncthreads();
#pragma unroll
    for (int i = 0; i < 2; ++i) {
        const int r = i * 32 + (t >> 3);
        const int c = (t & 7) << 3;
        *(bf16x8*)(Wt + (size_t)(n0 + r) * 1024 + k0 + c) = *(const bf16x8*)&T[r][c];
    }
}

// ---------------------------------------------------------------------------
// gemm_pack v2 (unchanged): depth-2 prefetch, counted vmcnt(4), granule XOR
// swizzle; epilogue scatters into MFMA-frag-packed Qp/Kp/Vp; Q pre-scaled.
// ---------------------------------------------------------------------------
__global__ __launch_bounds__(256, 3)
void gemm_pack(const short* __restrict__ Xb, const short* __restrict__ Wt,
               const float* __restrict__ bias, short* __restrict__ Qp,
               short* __restrict__ Kp, short* __restrict__ Vp) {
    __shared__ short Asm[3][128 * 32];
    __shared__ short Bsm[3][128 * 32];

    const int tid  = threadIdx.x;
    const int lane = tid & 63;
    const int l15  = lane & 15;
    const int lq   = lane >> 4;
    const int wave = tid >> 6;
    const int wr = wave >> 1, wc = wave & 1;

    const int bid = blockIdx.x;
    const int swz = (bid & 7) * 96 + (bid >> 3);
    const int m0 = (swz / 24) * 128, n0 = (swz % 24) * 128;

    const int srow = tid >> 2;
    const int scolsw = (((tid & 3) ^ (srow & 3)) << 3);

    f32x4 acc[4][4];
#pragma unroll
    for (int m = 0; m < 4; ++m)
#pragma unroll
        for (int n = 0; n < 4; ++n) acc[m][n] = (f32x4)(0.0f);

    auto stage = [&](int k0, int bb) {
#pragma unroll
        for (int i = 0; i < 2; ++i)
            async_ld16(Xb + (size_t)(m0 + i * 64 + srow) * 1024 + k0 + scolsw,
                       &Asm[bb][(i * 256 + wave * 64) * 8]);
#pragma unroll
        for (int i = 0; i < 2; ++i)
            async_ld16(Wt + (size_t)(n0 + i * 64 + srow) * 1024 + k0 + scolsw,
                       &Bsm[bb][(i * 256 + wave * 64) * 8]);
    };

    const int gsw = ((lq ^ (l15 & 3)) << 3);

    auto compute = [&](int bb) {
        bf16x8 af[4], bfv[4];
#pragma unroll
        for (int m = 0; m < 4; ++m)
            af[m] = *(const bf16x8*)&Asm[bb][(wr * 64 + m * 16 + l15) * 32 + gsw];
#pragma unroll
        for (int n = 0; n < 4; ++n)
            bfv[n] = *(const bf16x8*)&Bsm[bb][(wc * 64 + n * 16 + l15) * 32 + gsw];
#pragma unroll
        for (int m = 0; m < 4; ++m)
#pragma unroll
            for (int n = 0; n < 4; ++n) acc[m][n] = MFMA16(af[m], bfv[n], acc[m][n]);
    };

#define WAITV(N) do {                                           \
        asm volatile("s_waitcnt vmcnt(" #N ")" ::: "memory");   \
        __builtin_amdgcn_sched_barrier(0);                      \
        __builtin_amdgcn_s_barrier();                           \
        __builtin_amdgcn_sched_barrier(0);                      \
    } while (0)

    stage(0, 0);
    stage(32, 1);
#pragma unroll 1
    for (int kt = 0; kt < 30; ++kt) {
        WAITV(4);
        compute(kt % 3);
        stage((kt + 2) * 32, (kt + 2) % 3);
    }
    WAITV(4);
    compute(0);
    WAITV(0);
    compute(1);
#undef WAITV

    const float SCALE2 = 0.03125f * 1.44269504f;
    float bv[4];
#pragma unroll
    for (int n = 0; n < 4; ++n) bv[n] = bias[n0 + wc * 64 + n * 16 + l15];

    const size_t bbase = (size_t)(m0 >> 11) * 2097152;
    const int tokb = (m0 & 2047) + wr * 64;

#pragma unroll
    for (int n = 0; n < 4; ++n) {
        const int col = n0 + wc * 64 + n * 16 + l15;
        const int h   = col / 192;
        const int seg = (col >> 6) % 3;
        const int d   = col & 63;
        const size_t hb = bbase + (size_t)h * 131072;
        if (seg == 0) {
            const int cp = ((d >> 4) << 9) + (((d >> 3) & 1) << 8) + (d & 7);
#pragma unroll
            for (int m = 0; m < 4; ++m)
#pragma unroll
                for (int r = 0; r < 4; ++r) {
                    const int tok = tokb + m * 16 + (lq << 2) + r;
                    Qp[hb + ((size_t)(tok >> 5) << 11) + ((tok & 31) << 3) + cp] =
                        f2bf((acc[m][n][r] + bv[n]) * SCALE2);
                }
        } else if (seg == 1) {
            const int cp = ((d >> 4) << 10) + (((d >> 3) & 1) << 8) + (d & 7);
#pragma unroll
            for (int m = 0; m < 4; ++m)
#pragma unroll
                for (int r = 0; r < 4; ++r) {
                    const int tok = tokb + m * 16 + (lq << 2) + r;
                    Kp[hb + ((size_t)(tok >> 6) << 12) + (((tok >> 5) & 1) << 9)
                       + ((tok & 31) << 3) + cp] = f2bf(acc[m][n][r] + bv[n]);
                }
        } else {
            const int cp = ((d >> 5) << 11) + ((d & 31) << 3);
#pragma unroll
            for (int m = 0; m < 4; ++m)
#pragma unroll
                for (int r = 0; r < 4; ++r) {
                    const int tok = tokb + m * 16 + (lq << 2) + r;
                    Vp[hb + ((size_t)(tok >> 6) << 12) + (((tok >> 4) & 3) << 9)
                       + (((tok >> 3) & 1) << 8) + (tok & 7) + cp] =
                        f2bf(acc[m][n][r] + bv[n]);
                }
        }
    }
}

// ---------------------------------------------------------------------------
// attn_part v13b: v10 body + LPT chunk map, launch_bounds(64,2) — the proven
// no-spill register budget (R14: 104 VGPR, FETCH 12.4MB). 8 blocks/CU.
// LPT map: sizes monotone non-increasing in dispatch order.
//   u<32 : head chunk, qt=u+32, tiles [0,16), no diag
//   u>=32: s=16-((u-32)>>2) (16..1), j=(u-32)&3:
//          j<2 : single qtile qt=2s-2+j, tiles [0,s), diag
//          j>=2: tail chunk qt=2s+30+(j-2), tiles [16,s+16), diag
// Decode: xcd=id&7, idx=id>>3, u=idx>>2, bh=xcd*4+(idx&3). Grid 3072 x 64.
// ---------------------------------------------------------------------------
__global__ __launch_bounds__(64, 2)
void attn_part(const short* __restrict__ Qp, const short* __restrict__ Kp,
               const short* __restrict__ Vp, short* __restrict__ Po,
               float* __restrict__ Pm) {
    const int tid = threadIdx.x;
    const int l31 = tid & 31;
    const int hi  = tid >> 5;

    const int id  = blockIdx.x;       // 0..3071
    const int xcd = id & 7;
    const int idx = id >> 3;          // 0..383
    const int u   = idx >> 2;         // 0..95, ascending with id (LPT)
    const int bh  = xcd * 4 + (idx & 3);

    int qt, t0, t1;
    bool hasDiag;
    if (u < 32) {
        qt = u + 32; t0 = 0; t1 = 16; hasDiag = false;
    } else {
        const int s = 16 - ((u - 32) >> 2);     // 16..1
        const int j = (u - 32) & 3;
        if (j < 2) { qt = 2 * s - 2 + j;       t0 = 0;  t1 = s; }
        else       { qt = 2 * s + 30 + (j - 2); t0 = 16; t1 = s + 16; }
        hasDiag = true;
    }
    const int q0 = qt * 32;

    const size_t hb = (size_t)bh * 131072;

    bf16x8 qf[4];
    {
        const short* qp = Qp + hb + qt * 2048 + tid * 8;
#pragma unroll
        for (int dg = 0; dg < 4; ++dg) qf[dg] = *(const bf16x8*)(qp + dg * 512);
    }

    f32x16 o0 = (f32x16)(0.f), o1 = (f32x16)(0.f);
    float m_run = -1e30f, l_run = 0.f;
    const int qg = q0 + l31;

    bf16x8 kA[8], kB[8], va[8];

    auto loadK = [&](bf16x8 (&kr)[8], int t) {
        const short* p = Kp + hb + (size_t)t * 4096 + tid * 8;
#pragma unroll
        for (int f = 0; f < 8; ++f)
            kr[f] = *(const bf16x8*)(p + (f >> 1) * 1024 + (f & 1) * 512);
    };
    auto loadV = [&](int t) {
        const short* p = Vp + hb + (size_t)t * 4096 + tid * 8;
#pragma unroll
        for (int f = 0; f < 8; ++f) va[f] = *(const bf16x8*)(p + f * 512);
    };
    auto qk = [&](bf16x8 (&kr)[8], f32x16& c0, f32x16& c1) {
#pragma unroll
        for (int dg = 0; dg < 4; ++dg) {
            c0 = MFMA32(kr[2 * dg],     qf[dg], c0);
            c1 = MFMA32(kr[2 * dg + 1], qf[dg], c1);
        }
    };

    auto smpv = [&](f32x16& c0, f32x16& c1, int kv0, bool DIAG) {
        if (DIAG) {
#pragma unroll
            for (int r = 0; r < 16; ++r) {
                const int kvr = kv0 + (r & 3) + 8 * (r >> 2) + 4 * hi;
                if (kvr > qg)      c0[r] = -1e30f;
                if (kvr + 32 > qg) c1[r] = -1e30f;
            }
        }

        float mr[8];
#pragma unroll
        for (int r = 0; r < 8; ++r)
            mr[r] = fmaxf(fmaxf(c0[r], c0[8 + r]), fmaxf(c1[r], c1[8 + r]));
        float mx = fmaxf(fmaxf(fmaxf(mr[0], mr[1]), fmaxf(mr[2], mr[3])),
                         fmaxf(fmaxf(mr[4], mr[5]), fmaxf(mr[6], mr[7])));
        mx = fmaxf(mx, __shfl_xor(mx, 32, 64));

        if (!__all(mx <= m_run + 8.f)) {              // T13 defer-rescale
            const float mnew = fmaxf(m_run, mx);
            const float corr = fast_exp2(m_run - mnew);
            l_run *= corr;
            o0 = o0 * corr;
            o1 = o1 * corr;
            m_run = mnew;
        }

        float ps0 = 0.f, ps1 = 0.f, ps2 = 0.f, ps3 = 0.f;
#pragma unroll
        for (int r = 0; r < 4; ++r) {
            c0[r]      = fast_exp2(c0[r]      - m_run); ps0 += c0[r];
            c0[4 + r]  = fast_exp2(c0[4 + r]  - m_run); ps1 += c0[4 + r];
            c0[8 + r]  = fast_exp2(c0[8 + r]  - m_run); ps2 += c0[8 + r];
            c0[12 + r] = fast_exp2(c0[12 + r] - m_run); ps3 += c0[12 + r];
        }
#pragma unroll
        for (int r = 0; r < 4; ++r) {
            c1[r]      = fast_exp2(c1[r]      - m_run); ps0 += c1[r];
            c1[4 + r]  = fast_exp2(c1[4 + r]  - m_run); ps1 += c1[4 + r];
            c1[8 + r]  = fast_exp2(c1[8 + r]  - m_run); ps2 += c1[8 + r];
            c1[12 + r] = fast_exp2(c1[12 + r] - m_run); ps3 += c1[12 + r];
        }
        l_run += (ps0 + ps1) + (ps2 + ps3);

        bf16x8 bf00, bf01, bf10, bf11;
        MK_BFRAG(c0, 0, bf00);
        MK_BFRAG(c0, 8, bf01);
        MK_BFRAG(c1, 0, bf10);
        MK_BFRAG(c1, 8, bf11);

        o0 = MFMA32(va[0], bf00, o0);
        o0 = MFMA32(va[1], bf01, o0);
        o0 = MFMA32(va[2], bf10, o0);
        o0 = MFMA32(va[3], bf11, o0);
        o1 = MFMA32(va[4], bf00, o1);
        o1 = MFMA32(va[5], bf01, o1);
        o1 = MFMA32(va[6], bf10, o1);
        o1 = MFMA32(va[7], bf11, o1);
    };

    int t = t0;
    loadK(kA, t0);
#pragma unroll 1
    for (; t + 2 < t1; t += 2) {
        f32x16 c0 = (f32x16)(0.f), c1 = (f32x16)(0.f);
        qk(kA, c0, c1);
        loadK(kB, t + 1);          // K(t+1) hides under softmax+PV of t
        loadV(t);                  // V(t) hides under softmax of t
        smpv(c0, c1, t * 64, false);
        f32x16 d0 = (f32x16)(0.f), d1 = (f32x16)(0.f);
        qk(kB, d0, d1);
        loadK(kA, t + 2);
        loadV(t + 1);
        smpv(d0, d1, (t + 1) * 64, false);
    }
    if (t + 1 < t1) {
        f32x16 c0 = (f32x16)(0.f), c1 = (f32x16)(0.f);
        qk(kA, c0, c1);
        loadK(kB, t + 1);
        loadV(t);
        smpv(c0, c1, t * 64, false);
        f32x16 d0 = (f32x16)(0.f), d1 = (f32x16)(0.f);
        qk(kB, d0, d1);
        loadV(t + 1);
        smpv(d0, d1, (t + 1) * 64, hasDiag);
    } else {
        f32x16 c0 = (f32x16)(0.f), c1 = (f32x16)(0.f);
        qk(kA, c0, c1);
        loadV(t);
        smpv(c0, c1, t * 64, hasDiag);
    }

    // ---- epilogue ----
    const float l_tot = l_run + __shfl_xor(l_run, 32, 64);
    const float inv = 1.f / l_tot;
    const int prow = (bh * 96 + u) * 32 + l31;
#pragma unroll
    for (int g = 0; g < 4; ++g) {
        bf16x4 w4;
#pragma unroll
        for (int j = 0; j < 4; ++j) w4[j] = f2bf(o0[g * 4 + j] * inv);
        *(bf16x4*)&Po[(size_t)prow * 64 + 8 * g + 4 * hi] = w4;
#pragma unroll
        for (int j = 0; j < 4; ++j) w4[j] = f2bf(o1[g * 4 + j] * inv);
        *(bf16x4*)&Po[(size_t)prow * 64 + 32 + 4 * hi + 8 * g] = w4;
    }
    if (hi == 0) Pm[prow] = m_run + __log2f(l_tot);
}

// ---------------------------------------------------------------------------
// attn_combine: merge <=2 partials per q-row -> fp32 Out [B,H,S,64] flat.
// Inverse of the LPT map:
//   qt < 32 : single partial, s=(qt>>1)+1, u = 32 + (16-s)*4 + (qt&1)
//   qt >= 32: head u0 = qt-32; tail s=(qt>>1)-15, u1 = 32+(16-s)*4+2+(qt&1)
// ---------------------------------------------------------------------------
__global__ __launch_bounds__(256)
void attn_combine(const short* __restrict__ Po, const float* __restrict__ Pm,
                  float* __restrict__ Out) {
    const int idx = blockIdx.x * 256 + threadIdx.x;
    const int d4 = (idx & 15) << 2;
    const int rg = idx >> 4;
    const int q  = rg & 2047;
    const int bh = rg >> 11;
    const int qt = q >> 5, r = q & 31;

    f32x4 ov;
    if (qt < 32) {
        const int s = (qt >> 1) + 1;
        const int u = 32 + (16 - s) * 4 + (qt & 1);
        const int p0 = (bh * 96 + u) * 32 + r;
        bf16x4 a = *(const bf16x4*)&Po[(size_t)p0 * 64 + d4];
#pragma unroll
        for (int j = 0; j < 4; ++j) ov[j] = bf2f(a[j]);
    } else {
        const int u0 = qt - 32;
        const int s  = (qt >> 1) - 15;
        const int u1 = 32 + (16 - s) * 4 + 2 + (qt & 1);
        const int p0 = (bh * 96 + u0) * 32 + r;
        const int p1 = (bh * 96 + u1) * 32 + r;
        bf16x4 a = *(const bf16x4*)&Po[(size_t)p0 * 64 + d4];
        bf16x4 c = *(const bf16x4*)&Po[(size_t)p1 * 64 + d4];
        const float m0 = Pm[p0], m1 = Pm[p1];
        const float M = fmaxf(m0, m1);
        const float w0 = exp2f(m0 - M), w1 = exp2f(m1 - M);
        const float inv = 1.f / (w0 + w1);
#pragma unroll
        for (int j = 0; j < 4; ++j) ov[j] = (w0 * bf2f(a[j]) + w1 * bf2f(c[j])) * inv;
    }
    *(f32x4*)&Out[(size_t)rg * 64 + d4] = ov;
}

extern "C" void kernel_launch(void* const* d_in, const int* in_sizes, int n_in,
                              void* d_out, int out_size, void* d_ws, size_t ws_size,
                              hipStream_t stream) {
    const float* x  = (const float*)d_in[0];
    const float* W0 = (const float*)d_in[1];
    const float* b0 = (const float*)d_in[2];
    float* out = (float*)d_out;
    char* ws = (char*)d_ws;

    const size_t SEG_B = (size_t)32 * 131072 * 2;     // 8.39 MB per packed segment
    const size_t QKV_B = 3 * SEG_B;                   // 25.17 MB (Qp+Kp+Vp)
    const size_t XBF_B = (size_t)4096 * 1024 * 2;     // 8.39 MB
    const size_t PO_B  = (size_t)32 * 96 * 32 * 64 * 2;  // 12.58 MB

    short* qp = (short*)ws;
    short* kp = (short*)(ws + SEG_B);
    short* vp = (short*)(ws + 2 * SEG_B);
    short* xb = (short*)(ws + QKV_B);
    short* wt = (short*)(ws + QKV_B + XBF_B);
    short* po = (short*)(ws + QKV_B);                 // reuse xb/wt after gemm
    float* pm = (float*)(ws + QKV_B + PO_B);

    convert_fused<<<dim3(2816), dim3(256), 0, stream>>>(x, xb, W0, wt);
    gemm_pack<<<dim3(768), dim3(256), 0, stream>>>(xb, wt, b0, qp, kp, vp);
    attn_part<<<dim3(3072), dim3(64), 0, stream>>>(qp, kp, vp, po, pm);
    attn_combine<<<dim3(4096), dim3(256), 0, stream>>>(po, pm, out);
}